// Round 4
// baseline (1579.736 us; speedup 1.0000x reference)
//
#include <hip/hip_runtime.h>

typedef unsigned short u16;
typedef unsigned int u32;
typedef __attribute__((ext_vector_type(8))) short short8;
typedef __attribute__((ext_vector_type(4))) float floatx4;

#define LN_EPS 1e-5f
#define REG 6291456L   // 16*512*768 elems: Q|K|V region stride in qkvg

__device__ __forceinline__ float b2f(u16 u) {
    return __builtin_bit_cast(float, (u32)u << 16);
}
__device__ __forceinline__ u16 f2b(float f) {
    u32 x = __builtin_bit_cast(u32, f);
    return (u16)((x + 0x7fffu + ((x >> 16) & 1u)) >> 16);
}

// ---- 12-element vector load/store helpers (wave-per-row LN family) ----
// 12 elems: f32 = 48B (3x float4, 16B-aligned); bf16 = 24B (3x uint2, 8B-aligned)
__device__ __forceinline__ void ld12f(const float* p, float* d) {
    float4 a = ((const float4*)p)[0];
    float4 b = ((const float4*)p)[1];
    float4 c = ((const float4*)p)[2];
    d[0]=a.x; d[1]=a.y; d[2]=a.z;  d[3]=a.w;
    d[4]=b.x; d[5]=b.y; d[6]=b.z;  d[7]=b.w;
    d[8]=c.x; d[9]=c.y; d[10]=c.z; d[11]=c.w;
}
__device__ __forceinline__ void ld12b(const u16* p, float* d) {
    uint2 a = ((const uint2*)p)[0];
    uint2 b = ((const uint2*)p)[1];
    uint2 c = ((const uint2*)p)[2];
    d[0]=b2f((u16)a.x); d[1]=b2f((u16)(a.x>>16)); d[2]=b2f((u16)a.y);  d[3]=b2f((u16)(a.y>>16));
    d[4]=b2f((u16)b.x); d[5]=b2f((u16)(b.x>>16)); d[6]=b2f((u16)b.y);  d[7]=b2f((u16)(b.y>>16));
    d[8]=b2f((u16)c.x); d[9]=b2f((u16)(c.x>>16)); d[10]=b2f((u16)c.y); d[11]=b2f((u16)(c.y>>16));
}
__device__ __forceinline__ void st12f(float* p, const float* d) {
    ((float4*)p)[0] = make_float4(d[0], d[1], d[2], d[3]);
    ((float4*)p)[1] = make_float4(d[4], d[5], d[6], d[7]);
    ((float4*)p)[2] = make_float4(d[8], d[9], d[10], d[11]);
}
__device__ __forceinline__ void st12b(u16* p, const float* d) {
    uint2 a, b, c;
    a.x = (u32)f2b(d[0])  | ((u32)f2b(d[1])  << 16);
    a.y = (u32)f2b(d[2])  | ((u32)f2b(d[3])  << 16);
    b.x = (u32)f2b(d[4])  | ((u32)f2b(d[5])  << 16);
    b.y = (u32)f2b(d[6])  | ((u32)f2b(d[7])  << 16);
    c.x = (u32)f2b(d[8])  | ((u32)f2b(d[9])  << 16);
    c.y = (u32)f2b(d[10]) | ((u32)f2b(d[11]) << 16);
    ((uint2*)p)[0] = a; ((uint2*)p)[1] = b; ((uint2*)p)[2] = c;
}
// wave-wide (64-lane) butterfly sum of two values
__device__ __forceinline__ void wred2(float& a, float& b) {
#pragma unroll
    for (int o = 32; o > 0; o >>= 1) {
        a += __shfl_xor(a, o, 64);
        b += __shfl_xor(b, o, 64);
    }
}

// async global->LDS, 16B per lane; LDS dest must be base + lane*16 (m97/m104)
__device__ __forceinline__ void gload16(const u16* g, u16* l) {
    __builtin_amdgcn_global_load_lds(
        (const __attribute__((address_space(1))) void*)g,
        (__attribute__((address_space(3))) void*)l, 16, 0, 0);
}

// counted vmcnt wait (literal immediates required)
template<int N> __device__ __forceinline__ void wait_vm() {
    if constexpr (N == 0)      asm volatile("s_waitcnt vmcnt(0)" ::: "memory");
    else if constexpr (N == 4) asm volatile("s_waitcnt vmcnt(4)" ::: "memory");
    else if constexpr (N == 5) asm volatile("s_waitcnt vmcnt(5)" ::: "memory");
    else                       asm volatile("s_waitcnt vmcnt(0)" ::: "memory");
}

// ---------------------------------------------------------------------------
// Unified MFMA GEMM, 3-deep global_load_lds pipeline with counted vmcnt (T4).
// C = A[M,K] @ BT[Nb,K]^T (+bias), A/BT bf16. Block 256 = 4 waves (2x2).
// BN_=128: wave 64x64 (4x4 mfma); BN_=192: wave 64x96 (4x6). BK=32.
//
// LDS bank-conflict swizzle (rule #21: linear DMA dest + inverse-swizzled
// SOURCE + swizzled READ): slot s (16B) of row r holds global chunk
// s ^ ((r>>1)&3); read addr uses quad ^ ((r>>1)&3). Verified R1: conflicts 0.
//
// Pipeline (3 LDS buffers, 2 tiles in flight):
//   prologue: stage(0), stage(1)
//   iter t:   wait vmcnt(NCH)  [tile t done, t+1 still in flight]
//             s_barrier        [also protects buf[(t+2)%3] from readers]
//             stage(t+2) -> buf[(t+2)%3]
//             ds_read buf[t%3] + MFMA
//   last iter waits vmcnt(0). DMA latency spans two compute phases.
//
// Epilogues:
//  0 TOK   : C[(by*128+ml)*Nb + n] bf16                       [FFN, ld=Nb]
//  1 F32   : C[z*sC + (by*128+ml)*Nb + n] f32                 [scores]
//  3 VT    : C[h*393216 + (s*12+d)*512 + iL]  (s-blocked)     [row V^T]
//  4 ROWOUT: C[(sv*512+m)*768 + colbase + z*12 + d]           [row PV out]
//  8 QKROW : t=n/192 -> C+t*REG, head-major (s-major tiling)  [row Q,K]
//  9 COLQKV: t=n/192 -> C+t*REG, token layout (s-major)       [col q,k,v]
// bias idx: EPI 8/9: t*768+colbase+(n%192); else colbase+n.
// ---------------------------------------------------------------------------
template<int BN_, int EPI, int RELU, int HASBIAS, int SMAJ>
__global__ __launch_bounds__(256, 2) void gemm_dma(
    const u16* __restrict__ A, const u16* __restrict__ BT,
    const float* __restrict__ bias, void* __restrict__ C,
    int Nb, int K, long sA, long sB, long sC, int colbase)
{
    constexpr int NCH  = (128 + BN_) / 64;   // 16B DMA chunks per thread
    constexpr int JF   = BN_ / 32;           // B frags per wave
    constexpr int TILE = (128 + BN_) * 32;   // elems per LDS buffer
    __shared__ u16 lds[3 * TILE];            // triple-buffered A|B tile

    const u16* Az = A + (long)blockIdx.z * sA;
    const u16* Bz = BT + (long)blockIdx.z * sB;
    const int n0 = blockIdx.x * BN_;
    const int tid = threadIdx.x;
    const int lane = tid & 63;
    const int wm = ((tid >> 6) >> 1) * 64;
    const int wn = ((tid >> 6) & 1) * (BN_ / 2);
    const int lrow = lane & 15;
    const int quad = lane >> 4;

    floatx4 acc[4][JF];
#pragma unroll
    for (int i = 0; i < 4; i++)
#pragma unroll
        for (int j = 0; j < JF; j++)
            acc[i][j] = (floatx4){0.f, 0.f, 0.f, 0.f};

    // ---- precompute staging sources (kt added at issue) + LDS offsets ----
    const u16* sbase[NCH];
    int doff[NCH];
#pragma unroll
    for (int it = 0; it < NCH; it++) {
        const int idx = tid + it * 256;
        const int slot = idx & 3;
        doff[it] = idx * 8;
        if (idx < 512) {                     // A chunks (wave-uniform branch)
            const int row = idx >> 2;
            const int ch  = (slot ^ ((row >> 1) & 3)) * 8;   // inverse swizzle
            const long grow = SMAJ
                ? ((long)(row >> 1) * 512 + (blockIdx.y << 1) + (row & 1))
                : ((long)blockIdx.y * 128 + row);
            sbase[it] = Az + grow * K + ch;
        } else {                             // B chunks
            const int row = (idx - 512) >> 2;
            const int ch  = (slot ^ ((row >> 1) & 3)) * 8;
            sbase[it] = Bz + (long)(n0 + row) * K + ch;
        }
    }

    // ---- precompute swizzled fragment read offsets ----
    int aoff[4], boff[JF];
#pragma unroll
    for (int i = 0; i < 4; i++) {
        const int r = wm + i * 16 + lrow;
        aoff[i] = r * 32 + ((quad ^ ((r >> 1) & 3)) * 8);
    }
#pragma unroll
    for (int j = 0; j < JF; j++) {
        const int r = wn + j * 16 + lrow;
        boff[j] = 4096 + r * 32 + ((quad ^ ((r >> 1) & 3)) * 8);
    }

    // ---- prologue: stage tiles 0 and 1 ----
#pragma unroll
    for (int it = 0; it < NCH; it++)
        gload16(sbase[it], &lds[doff[it]]);
    if (K > 32) {
#pragma unroll
        for (int it = 0; it < NCH; it++)
            gload16(sbase[it] + 32, &lds[TILE + doff[it]]);
    }
    __builtin_amdgcn_sched_barrier(0);

    // ---- main loop: one barrier + one counted wait per K-step ----
    int bufc = 0;                            // buffer holding tile t
    for (int kt = 0; kt < K; kt += 32) {
        if (kt + 32 >= K) wait_vm<0>();      // last tile: drain
        else              wait_vm<NCH>();    // tile t done, t+1 in flight
        __builtin_amdgcn_s_barrier();
        __builtin_amdgcn_sched_barrier(0);

        if (kt + 64 < K) {                   // stage tile t+2
            int nb = bufc + 2; if (nb >= 3) nb -= 3;
            const int nbo = nb * TILE;
#pragma unroll
            for (int it = 0; it < NCH; it++)
                gload16(sbase[it] + kt + 64, &lds[nbo + doff[it]]);
        }
        __builtin_amdgcn_sched_barrier(0);   // stage issues before ds_reads

        const int b0 = bufc * TILE;
        short8 af[4], bfr[JF];
#pragma unroll
        for (int i = 0; i < 4; i++)
            af[i] = *(const short8*)&lds[b0 + aoff[i]];
#pragma unroll
        for (int j = 0; j < JF; j++)
            bfr[j] = *(const short8*)&lds[b0 + boff[j]];
#pragma unroll
        for (int i = 0; i < 4; i++)
#pragma unroll
            for (int j = 0; j < JF; j++)
                acc[i][j] = __builtin_amdgcn_mfma_f32_16x16x32_bf16(
                    af[i], bfr[j], acc[i][j], 0, 0, 0);

        __builtin_amdgcn_sched_barrier(0);   // keep compute inside the phase
        if (++bufc == 3) bufc = 0;
    }

    // D element: row = quad*4+r, col = lane&15 (verified m89/m91)
    const int z = blockIdx.z;
#pragma unroll
    for (int j = 0; j < JF; j++) {
        const int n = n0 + wn + j * 16 + lrow;
        int t = 0, jj = n;
        if (EPI == 8 || EPI == 9) { t = n / 192; jj = n - t * 192; }
        const int hl = jj / 12;
        const int cc = jj - hl * 12;
        float bv = 0.f;
        if (HASBIAS)
            bv = (EPI == 8 || EPI == 9) ? bias[t * 768 + colbase + jj]
                                        : bias[colbase + n];
#pragma unroll
        for (int i = 0; i < 4; i++) {
            const int mb = wm + i * 16 + quad * 4;
#pragma unroll
            for (int r = 0; r < 4; r++) {
                const int ml = mb + r;
                float v = acc[i][j][r] + bv;
                if (RELU) v = fmaxf(v, 0.f);
                if (EPI == 0) {
                    const long m = (long)blockIdx.y * 128 + ml;
                    ((u16*)C)[m * Nb + n] = f2b(v);
                } else if (EPI == 1) {
                    const long m = (long)blockIdx.y * 128 + ml;
                    ((float*)C)[(long)z * sC + m * Nb + n] = v;
                } else if (EPI == 3) {
                    const int gm = blockIdx.y * 128 + ml;
                    const int s = gm >> 9, iL = gm & 511;
                    ((u16*)C)[(long)hl * 393216 + (long)(s * 12 + cc) * 512 + iL] = f2b(v);
                } else if (EPI == 4) {
                    const int m = blockIdx.y * 128 + ml;    // hl here = s-value
                    ((u16*)C)[((long)hl * 512 + m) * 768 + colbase + z * 12 + cc] = f2b(v);
                } else if (EPI == 8) {
                    const int s = ml >> 1, iL = (blockIdx.y << 1) + (ml & 1);
                    ((u16*)C)[(long)t * REG + ((long)hl * 512 + iL) * 768 + s * 12 + cc] = f2b(v);
                } else if (EPI == 9) {
                    const int s = ml >> 1, l = (blockIdx.y << 1) + (ml & 1);
                    ((u16*)C)[(long)t * REG + (long)hl * 393216 + (long)l * 768 + s * 12 + cc] = f2b(v);
                }
            }
        }
    }
}

// ---------------------------------------------------------------------------
// x (f32) -> xb (bf16), 8 elems/thread
// ---------------------------------------------------------------------------
__global__ __launch_bounds__(256) void cast_kernel(
    const float* __restrict__ X, u16* __restrict__ Xb)
{
    const long i = ((long)blockIdx.x * 256 + threadIdx.x) * 8;
    float4 a = *(const float4*)(X + i);
    float4 b = *(const float4*)(X + i + 4);
    u16 t8[8] = { f2b(a.x), f2b(a.y), f2b(a.z), f2b(a.w),
                  f2b(b.x), f2b(b.y), f2b(b.z), f2b(b.w) };
    *(uint4*)(Xb + i) = *(const uint4*)t8;
}

// ---------------------------------------------------------------------------
// 32x32 tiled transpose + cast: Out[c][r] = bf16(In[r][c]); Out ld = R
// ---------------------------------------------------------------------------
__global__ __launch_bounds__(256) void transpose_kernel(
    const float* __restrict__ In, u16* __restrict__ Out, int R, int Ccols)
{
    __shared__ u16 tile[32][33];
    int tx = threadIdx.x & 31;
    int ty = threadIdx.x >> 5;
    int c0 = blockIdx.x * 32;
    int r0 = blockIdx.y * 32;
#pragma unroll
    for (int rr = 0; rr < 32; rr += 8)
        tile[ty + rr][tx] = f2b(In[(long)(r0 + ty + rr) * Ccols + c0 + tx]);
    __syncthreads();
#pragma unroll
    for (int rr = 0; rr < 32; rr += 8)
        Out[(long)(c0 + ty + rr) * R + r0 + tx] = tile[tx][ty + rr];
}

// W[768][2304] -> wPqk[1536][768]: row p: hg=p/384, t=(p%384)/192, j=p%192
__global__ __launch_bounds__(256) void pack_qk_kernel(
    const float* __restrict__ In, u16* __restrict__ Out)
{
    __shared__ u16 tile[32][33];
    int tx = threadIdx.x & 31;
    int ty = threadIdx.x >> 5;
    int p0 = blockIdx.x * 32;
    int k0 = blockIdx.y * 32;
    int hg = p0 / 384, rem = p0 % 384;
    int t = rem / 192, j0 = rem % 192;
    int c0 = t * 768 + hg * 192 + j0;
#pragma unroll
    for (int rr = 0; rr < 32; rr += 8)
        tile[ty + rr][tx] = f2b(In[(long)(k0 + ty + rr) * 2304 + c0 + tx]);
    __syncthreads();
#pragma unroll
    for (int rr = 0; rr < 32; rr += 8)
        Out[(long)(p0 + ty + rr) * 768 + k0 + tx] = tile[tx][ty + rr];
}

// W[768][2304] -> wPv[768][768]: row p: hg=p/192, j=p%192 -> col 1536+hg*192+j
__global__ __launch_bounds__(256) void pack_v_kernel(
    const float* __restrict__ In, u16* __restrict__ Out)
{
    __shared__ u16 tile[32][33];
    int tx = threadIdx.x & 31;
    int ty = threadIdx.x >> 5;
    int p0 = blockIdx.x * 32;
    int k0 = blockIdx.y * 32;
    int hg = p0 / 192, j0 = p0 % 192;
    int c0 = 1536 + hg * 192 + j0;
#pragma unroll
    for (int rr = 0; rr < 32; rr += 8)
        tile[ty + rr][tx] = f2b(In[(long)(k0 + ty + rr) * 2304 + c0 + tx]);
    __syncthreads();
#pragma unroll
    for (int rr = 0; rr < 32; rr += 8)
        Out[(long)(p0 + ty + rr) * 768 + k0 + tx] = tile[tx][ty + rr];
}

// W[768][2304] -> wPcol[2304][768]: row p: hg=p/576, t=(p%576)/192, j=p%192
__global__ __launch_bounds__(256) void qkv_pack_kernel(
    const float* __restrict__ In, u16* __restrict__ Out)
{
    __shared__ u16 tile[32][33];
    int tx = threadIdx.x & 31;
    int ty = threadIdx.x >> 5;
    int p0 = blockIdx.x * 32;
    int k0 = blockIdx.y * 32;
    int hg = p0 / 576, r0 = p0 % 576;
    int t = r0 / 192, j0 = r0 % 192;
    int c0 = t * 768 + hg * 192 + j0;
#pragma unroll
    for (int rr = 0; rr < 32; rr += 8)
        tile[ty + rr][tx] = f2b(In[(long)(k0 + ty + rr) * 2304 + c0 + tx]);
    __syncthreads();
#pragma unroll
    for (int rr = 0; rr < 32; rr += 8)
        Out[(long)(p0 + ty + rr) * 768 + k0 + tx] = tile[tx][ty + rr];
}

// ---------------------------------------------------------------------------
// Row softmax over 512 (f32 scores -> bf16 probs); wave-per-row, 4 rows/block
// ---------------------------------------------------------------------------
__global__ __launch_bounds__(256) void softmax_kernel(
    const float* __restrict__ S, u16* __restrict__ P)
{
    const long r = (long)blockIdx.x * 4 + (threadIdx.x >> 6);
    const int lane = threadIdx.x & 63;
    const float* sp = S + r * 512 + lane * 8;
    float4 a = ((const float4*)sp)[0];
    float4 b = ((const float4*)sp)[1];
    float v[8] = {a.x, a.y, a.z, a.w, b.x, b.y, b.z, b.w};
    float mx = v[0];
#pragma unroll
    for (int e = 1; e < 8; e++) mx = fmaxf(mx, v[e]);
#pragma unroll
    for (int o = 32; o > 0; o >>= 1) mx = fmaxf(mx, __shfl_xor(mx, o, 64));
    float sum = 0.f;
#pragma unroll
    for (int e = 0; e < 8; e++) { v[e] = __expf(v[e] - mx); sum += v[e]; }
#pragma unroll
    for (int o = 32; o > 0; o >>= 1) sum += __shfl_xor(sum, o, 64);
    float inv = 1.0f / sum;
    uint4 o4;
    o4.x = (u32)f2b(v[0] * inv) | ((u32)f2b(v[1] * inv) << 16);
    o4.y = (u32)f2b(v[2] * inv) | ((u32)f2b(v[3] * inv) << 16);
    o4.z = (u32)f2b(v[4] * inv) | ((u32)f2b(v[5] * inv) << 16);
    o4.w = (u32)f2b(v[6] * inv) | ((u32)f2b(v[7] * inv) << 16);
    *(uint4*)(P + r * 512 + lane * 8) = o4;
}

// ---------------------------------------------------------------------------
// out = LN(Xa + Xb) * g + be ; wave-per-row (lane owns 12 elems), 4 rows/block
// Xa dtype AF (1=f32), Xb dtype BF, out OF. No LDS, shuffle reductions.
// ---------------------------------------------------------------------------
template<int AF, int BF, int OF>
__global__ __launch_bounds__(256) void ln_add_kernel(
    const void* __restrict__ Xa, const void* __restrict__ Xb,
    const float* __restrict__ g, const float* __restrict__ be,
    void* __restrict__ Out)
{
    const long r = (long)blockIdx.x * 4 + (threadIdx.x >> 6);
    const int lane = threadIdx.x & 63;
    const long c0 = r * 768 + lane * 12;
    float va[12], vb[12], v[12];
    if (AF) ld12f((const float*)Xa + c0, va);
    else    ld12b((const u16*)Xa + c0, va);
    if (BF) ld12f((const float*)Xb + c0, vb);
    else    ld12b((const u16*)Xb + c0, vb);
    float sm = 0.f, s2 = 0.f;
#pragma unroll
    for (int e = 0; e < 12; e++) {
        v[e] = va[e] + vb[e];
        sm += v[e]; s2 += v[e] * v[e];
    }
    wred2(sm, s2);
    float mean = sm * (1.0f / 768.0f);
    float var  = s2 * (1.0f / 768.0f) - mean * mean;
    float rstd = rsqrtf(var + LN_EPS);
    float gv[12], bv[12], o[12];
    ld12f(g + lane * 12, gv);
    ld12f(be + lane * 12, bv);
#pragma unroll
    for (int e = 0; e < 12; e++)
        o[e] = (v[e] - mean) * rstd * gv[e] + bv[e];
    if (OF) st12f((float*)Out + c0, o);
    else    st12b((u16*)Out + c0, o);
}

// ---------------------------------------------------------------------------
// Fused double-LN: y(f32) = LN2( X + LN1(A + B) ); also writes ybf (bf16).
// Wave-per-row, 4 rows/block, shuffle reductions, no LDS.
// ---------------------------------------------------------------------------
__global__ __launch_bounds__(256) void ln_ln_kernel(
    const u16* __restrict__ A, const u16* __restrict__ B,
    const float* __restrict__ X,
    const float* __restrict__ g1, const float* __restrict__ be1,
    const float* __restrict__ g2, const float* __restrict__ be2,
    float* __restrict__ Out, u16* __restrict__ Outb)
{
    const long r = (long)blockIdx.x * 4 + (threadIdx.x >> 6);
    const int lane = threadIdx.x & 63;
    const long c0 = r * 768 + lane * 12;
    float ua[12], ub[12], u[12];
    ld12b(A + c0, ua);
    ld12b(B + c0, ub);
    float sm = 0.f, s2 = 0.f;
#pragma unroll
    for (int e = 0; e < 12; e++) {
        u[e] = ua[e] + ub[e];
        sm += u[e]; s2 += u[e] * u[e];
    }
    wred2(sm, s2);
    float mean1 = sm * (1.0f / 768.0f);
    float var1  = s2 * (1.0f / 768.0f) - mean1 * mean1;
    float rstd1 = rsqrtf(var1 + LN_EPS);

    float xx[12], g1v[12], b1v[12], w[12];
    ld12f(X + c0, xx);
    ld12f(g1 + lane * 12, g1v);
    ld12f(be1 + lane * 12, b1v);
    sm = 0.f; s2 = 0.f;
#pragma unroll
    for (int e = 0; e < 12; e++) {
        float tv = (u[e] - mean1) * rstd1 * g1v[e] + b1v[e];
        w[e] = xx[e] + tv;
        sm += w[e]; s2 += w[e] * w[e];
    }
    wred2(sm, s2);
    float mean2 = sm * (1.0f / 768.0f);
    float var2  = s2 * (1.0f / 768.0f) - mean2 * mean2;
    float rstd2 = rsqrtf(var2 + LN_EPS);

    float g2v[12], b2v[12], o[12];
    ld12f(g2 + lane * 12, g2v);
    ld12f(be2 + lane * 12, b2v);
#pragma unroll
    for (int e = 0; e < 12; e++)
        o[e] = (w[e] - mean2) * rstd2 * g2v[e] + b2v[e];
    st12f(Out + c0, o);
    st12b(Outb + c0, o);
}

// ---------------------------------------------------------------------------
// Col attention for one 16-head group. Slices: [h'][l][s*12+c].
// Block = (h', l), 64 threads; thread i = query S-row. Vector uint2 loads.
// ---------------------------------------------------------------------------
__global__ __launch_bounds__(64) void col_attn_kernel(
    const u16* __restrict__ qc, const u16* __restrict__ kc,
    const u16* __restrict__ vc, u16* __restrict__ Out, int hbase)
{
    const int hh = blockIdx.x >> 9;
    const int l  = blockIdx.x & 511;
    const int i  = threadIdx.x;
    const long base = ((long)hh * 512 + l) * 768 + (long)i * 12;
    __shared__ float Ks[64][12];
    __shared__ float Vs[64][12];
    float q[12], kk[12], vv[12];
    ld12b(qc + base, q);
    ld12b(kc + base, kk);
    ld12b(vc + base, vv);
#pragma unroll
    for (int c = 0; c < 12; c++) { Ks[i][c] = kk[c]; Vs[i][c] = vv[c]; }
    __syncthreads();
    float sc[64];
#pragma unroll
    for (int j = 0; j < 64; j++) {
        float a = 0.f;
#pragma unroll
        for (int c = 0; c < 12; c++) a += q[c] * Ks[j][c];
        sc[j] = a;
    }
    float m = sc[0];
#pragma unroll
    for (int j = 1; j < 64; j++) m = fmaxf(m, sc[j]);
    float sum = 0.f;
#pragma unroll
    for (int j = 0; j < 64; j++) { sc[j] = __expf(sc[j] - m); sum += sc[j]; }
    float inv = 1.0f / sum;
    float o[12];
#pragma unroll
    for (int c = 0; c < 12; c++) o[c] = 0.f;
#pragma unroll
    for (int j = 0; j < 64; j++) {
        float p = sc[j] * inv;
#pragma unroll
        for (int c = 0; c < 12; c++) o[c] += p * Vs[j][c];
    }
    u16* op = Out + ((long)i * 512 + l) * 768 + hbase + hh * 12;
    st12b(op, o);
}

// ---------------------------------------------------------------------------
extern "C" void kernel_launch(void* const* d_in, const int* in_sizes, int n_in,
                              void* d_out, int out_size, void* d_ws, size_t ws_size,
                              hipStream_t stream)
{
    (void)in_sizes; (void)n_in; (void)out_size; (void)ws_size;

    const float* x     = (const float*)d_in[0];
    const float* w_row = (const float*)d_in[1];
    const float* b_row = (const float*)d_in[2];
    const float* w_col = (const float*)d_in[3];
    const float* b_col = (const float*)d_in[4];
    const float* g_a1  = (const float*)d_in[5];
    const float* be_a1 = (const float*)d_in[6];
    const float* g_a2  = (const float*)d_in[7];
    const float* be_a2 = (const float*)d_in[8];
    const float* w1    = (const float*)d_in[9];
    const float* b1f   = (const float*)d_in[10];
    const float* w2    = (const float*)d_in[11];
    const float* b2f_  = (const float*)d_in[12];
    const float* g_n1  = (const float*)d_in[13];
    const float* be_n1 = (const float*)d_in[14];
    const float* g_n2  = (const float*)d_in[15];
    const float* be_n2 = (const float*)d_in[16];
    float* outp = (float*)d_out;

    // ---- workspace layout (~172 MiB; matches R3/R4 footprint) ----
    char* wp = (char*)d_ws;
    auto alloc = [&](size_t bytes) -> void* {
        void* p = (void*)wp;
        wp += (bytes + 255) & ~(size_t)255;
        return p;
    };
    u16*   wPqk   = (u16*)alloc((size_t)1536 * 768 * 2);        // 2.25 MiB
    u16*   wPv    = (u16*)alloc((size_t)768 * 768 * 2);         // 1.13 MiB
    u16*   wPcol  = (u16*)alloc((size_t)2304 * 768 * 2);        // 3.38 MiB
    u16*   w1T    = (u16*)alloc((size_t)3072 * 768 * 2);        // 4.5 MiB
    u16*   w2T    = (u16*)alloc((size_t)768 * 3072 * 2);        // 4.5 MiB
    u16*   bufA   = (u16*)alloc((size_t)32768 * 768 * 2);       // 48 MiB: rowout/colout/ffb
    u16*   bufB   = (u16*)alloc((size_t)32768 * 768 * 2);       // 48 MiB: xb -> out1 -> ybf
    u16*   qkvg   = (u16*)alloc((size_t)3 * 16 * 512 * 768 * 2);// 36 MiB: Q|K|V group
    float* scores = (float*)alloc((size_t)16 * 512 * 512 * 4);  // 16 MiB
    u16*   probs  = (u16*)alloc((size_t)16 * 512 * 512 * 2);    // 8 MiB
    u16*   hidden = qkvg;    // alias: qkvg+scores dead during FFN (48 MiB)
    u16*   xb     = bufB;    // bf16 x; dead before out1 is written
    u16*   ybf    = bufB;    // bf16 y; out1 dead when ln_ln runs
    float* y      = outp;    // f32 y in d_out until final in-place LN

    // ---- weight packing (f32 -> bf16) ----
    pack_qk_kernel<<<dim3(48, 24), 256, 0, stream>>>(w_row, wPqk);
    pack_v_kernel<<<dim3(24, 24), 256, 0, stream>>>(w_row, wPv);
    qkv_pack_kernel<<<dim3(72, 24), 256, 0, stream>>>(w_col, wPcol);
    transpose_kernel<<<dim3(96, 24), 256, 0, stream>>>(w1, w1T, 768, 3072);
    transpose_kernel<<<dim3(24, 96), 256, 0, stream>>>(w2, w2T, 3072, 768);
    cast_kernel<<<12288, 256, 0, stream>>>(x, xb);

    // ---- row (tied) attention, 4 groups of 16 heads ----
    for (int hg = 0; hg < 4; hg++) {
        // Q,K (N=384, s-major, dense head-major writes)
        gemm_dma<192, 8, 0, 1, 1><<<dim3(2, 256), 256, 0, stream>>>(
            xb, wPqk + (long)hg * 384 * 768, b_row, qkvg,
            384, 768, 0, 0, 0, hg * 192);
        // V (N=192, s-blocked, dense V^T writes)
        gemm_dma<192, 3, 0, 1, 0><<<dim3(1, 256), 256, 0, stream>>>(
            xb, wPv + (long)hg * 192 * 768, b_row, qkvg + 2 * REG,
            192, 768, 0, 0, 0, 1536 + hg * 192);
        // scores = Q @ K^T (batched over 16 heads)
        gemm_dma<128, 1, 0, 0, 0><<<dim3(4, 4, 16), 256, 0, stream>>>(
            qkvg, qkvg + REG, nullptr, scores,
            512, 768, (long)512 * 768, (long)512 * 768, (long)512 * 512, 0);
        softmax_kernel<<<2048, 256, 0, stream>>>(scores, probs);
        // rowout = P @ V^T^T (batched over 16 heads)
        gemm_dma<128, 4, 0, 0, 0><<<dim3(6, 4, 16), 256, 0, stream>>>(
            probs, qkvg + 2 * REG, nullptr, bufA,
            768, 512, (long)512 * 512, (long)768 * 512, 0, hg * 192);
    }
    // out1 = LN(x + rowout)   (xb dead from here; bufB becomes out1)
    ln_add_kernel<1, 0, 0><<<8192, 256, 0, stream>>>(x, bufA, g_a1, be_a1, bufB);

    // ---- col attention, 4 groups of 16 heads ----
    for (int hg = 0; hg < 4; hg++) {
        gemm_dma<192, 9, 0, 1, 1><<<dim3(3, 256), 256, 0, stream>>>(
            bufB, wPcol + (long)hg * 576 * 768, b_col, qkvg,
            576, 768, 0, 0, 0, hg * 192);
        col_attn_kernel<<<8192, 64, 0, stream>>>(
            qkvg, qkvg + REG, qkvg + 2 * REG, bufA, hg * 192);
    }
    // y = LN(x + LN(out1 + colout)) -> d_out (f32) + ybf (bf16, row-local alias)
    ln_ln_kernel<<<8192, 256, 0, stream>>>(
        bufB, bufA, x, g_a2, be_a2, g_n1, be_n1, y, ybf);

    // ---- FFN, 4 chunks of 8192 rows (hidden overlays qkvg+scores) ----
    for (int mc = 0; mc < 4; mc++) {
        const long off = (long)mc * 8192 * 768;
        gemm_dma<192, 0, 1, 1, 0><<<dim3(16, 64), 256, 0, stream>>>(
            ybf + off, w1T, b1f, hidden, 3072, 768, 0, 0, 0, 0);
        gemm_dma<192, 0, 0, 1, 0><<<dim3(4, 64), 256, 0, stream>>>(
            hidden, w2T, b2f_, bufA + off, 768, 3072, 0, 0, 0, 0);
    }
    // final: out = LN(y + ffb), in-place over d_out (per-row, block-local)
    ln_add_kernel<1, 0, 1><<<8192, 256, 0, stream>>>(y, bufA, g_n2, be_n2, outp);
}

// Round 7
// 1431.027 us; speedup vs baseline: 1.1039x; 1.1039x over previous
//
#include <hip/hip_runtime.h>

typedef unsigned short u16;
typedef unsigned int u32;
typedef __attribute__((ext_vector_type(8))) short short8;
typedef __attribute__((ext_vector_type(4))) float floatx4;

#define LN_EPS 1e-5f
#define REG 6291456L   // 16*512*768 elems: per-16-head Q|K|V region stride (fallback)

__device__ __forceinline__ float b2f(u16 u) {
    return __builtin_bit_cast(float, (u32)u << 16);
}
__device__ __forceinline__ u16 f2b(float f) {
    u32 x = __builtin_bit_cast(u32, f);
    return (u16)((x + 0x7fffu + ((x >> 16) & 1u)) >> 16);
}

// ---- 12-element vector load/store helpers (wave-per-row LN family) ----
__device__ __forceinline__ void ld12f(const float* p, float* d) {
    float4 a = ((const float4*)p)[0];
    float4 b = ((const float4*)p)[1];
    float4 c = ((const float4*)p)[2];
    d[0]=a.x; d[1]=a.y; d[2]=a.z;  d[3]=a.w;
    d[4]=b.x; d[5]=b.y; d[6]=b.z;  d[7]=b.w;
    d[8]=c.x; d[9]=c.y; d[10]=c.z; d[11]=c.w;
}
__device__ __forceinline__ void ld12b(const u16* p, float* d) {
    uint2 a = ((const uint2*)p)[0];
    uint2 b = ((const uint2*)p)[1];
    uint2 c = ((const uint2*)p)[2];
    d[0]=b2f((u16)a.x); d[1]=b2f((u16)(a.x>>16)); d[2]=b2f((u16)a.y);  d[3]=b2f((u16)(a.y>>16));
    d[4]=b2f((u16)b.x); d[5]=b2f((u16)(b.x>>16)); d[6]=b2f((u16)b.y);  d[7]=b2f((u16)(b.y>>16));
    d[8]=b2f((u16)c.x); d[9]=b2f((u16)(c.x>>16)); d[10]=b2f((u16)c.y); d[11]=b2f((u16)(c.y>>16));
}
__device__ __forceinline__ void st12f(float* p, const float* d) {
    ((float4*)p)[0] = make_float4(d[0], d[1], d[2], d[3]);
    ((float4*)p)[1] = make_float4(d[4], d[5], d[6], d[7]);
    ((float4*)p)[2] = make_float4(d[8], d[9], d[10], d[11]);
}
__device__ __forceinline__ void st12b(u16* p, const float* d) {
    uint2 a, b, c;
    a.x = (u32)f2b(d[0])  | ((u32)f2b(d[1])  << 16);
    a.y = (u32)f2b(d[2])  | ((u32)f2b(d[3])  << 16);
    b.x = (u32)f2b(d[4])  | ((u32)f2b(d[5])  << 16);
    b.y = (u32)f2b(d[6])  | ((u32)f2b(d[7])  << 16);
    c.x = (u32)f2b(d[8])  | ((u32)f2b(d[9])  << 16);
    c.y = (u32)f2b(d[10]) | ((u32)f2b(d[11]) << 16);
    ((uint2*)p)[0] = a; ((uint2*)p)[1] = b; ((uint2*)p)[2] = c;
}
__device__ __forceinline__ void wred2(float& a, float& b) {
#pragma unroll
    for (int o = 32; o > 0; o >>= 1) {
        a += __shfl_xor(a, o, 64);
        b += __shfl_xor(b, o, 64);
    }
}

// async global->LDS, 16B per lane; LDS dest must be base + lane*16 (m97/m104)
__device__ __forceinline__ void gload16(const u16* g, u16* l) {
    __builtin_amdgcn_global_load_lds(
        (const __attribute__((address_space(1))) void*)g,
        (__attribute__((address_space(3))) void*)l, 16, 0, 0);
}

// counted vmcnt wait (literal immediates required)
template<int N> __device__ __forceinline__ void wait_vm() {
    if constexpr (N == 0)      asm volatile("s_waitcnt vmcnt(0)" ::: "memory");
    else if constexpr (N == 4) asm volatile("s_waitcnt vmcnt(4)" ::: "memory");
    else if constexpr (N == 5) asm volatile("s_waitcnt vmcnt(5)" ::: "memory");
    else                       asm volatile("s_waitcnt vmcnt(0)" ::: "memory");
}

// ---------------------------------------------------------------------------
// Unified MFMA GEMM, 3-deep global_load_lds pipeline with counted vmcnt (T4).
// C = A[M,K] @ BT[Nb,K]^T (+bias), A/BT bf16. Block 256 = 4 waves (2x2).
// BN_=128: wave 64x64 (4x4 mfma); BN_=192: wave 64x96 (4x6). BK=32.
//
// LDS swizzle: slot s (16B) of row r holds global chunk s ^ ((r>>1)&3);
// read addr uses quad ^ ((r>>1)&3). Verified R1: bank conflicts 0.
//
// Pipeline (3 LDS buffers, 2 tiles in flight): wait vmcnt(NCH) -> barrier ->
// stage(t+2) -> ds_read+MFMA on buf t. Last iter drains vmcnt(0).
//
// Epilogues (hG = head-group within a merged launch; reduces to old behavior
// when the launch spans one group -> hG==0):
//  0 TOK   : C[(by*128+ml)*Nb + n] bf16                       [FFN, ld=Nb]
//  1 F32   : C[z*sC + (by*128+ml)*Nb + n] f32                 [scores]
//  3 VT    : head=n/12: C[head*393216 + (s*12+cc)*512 + iL]   [row V^T]
//  4 ROWOUT: C[(sv*512+m)*768 + colbase + z*12 + cc]          [row PV out]
//  8 QKROW : hG=n/384, t=(n%384)/192: C[t*sC + head-major]    [row Q,K]
//  9 COLQKV: hG=n/576, t=(n%576)/192: C[t*sC + token layout]  [col q,k,v]
// EPI 8/9: sC = Q|K|V region stride (elems); bias idx t*768+colbase+hG*192+jj.
// ---------------------------------------------------------------------------
template<int BN_, int EPI, int RELU, int HASBIAS, int SMAJ>
__global__ __launch_bounds__(256, 2) void gemm_dma(
    const u16* __restrict__ A, const u16* __restrict__ BT,
    const float* __restrict__ bias, void* __restrict__ C,
    int Nb, int K, long sA, long sB, long sC, int colbase)
{
    constexpr int NCH  = (128 + BN_) / 64;   // 16B DMA chunks per thread
    constexpr int JF   = BN_ / 32;           // B frags per wave
    constexpr int TILE = (128 + BN_) * 32;   // elems per LDS buffer
    __shared__ u16 lds[3 * TILE];            // triple-buffered A|B tile

    const u16* Az = A + (long)blockIdx.z * sA;
    const u16* Bz = BT + (long)blockIdx.z * sB;
    const int n0 = blockIdx.x * BN_;
    const int tid = threadIdx.x;
    const int lane = tid & 63;
    const int wm = ((tid >> 6) >> 1) * 64;
    const int wn = ((tid >> 6) & 1) * (BN_ / 2);
    const int lrow = lane & 15;
    const int quad = lane >> 4;

    floatx4 acc[4][JF];
#pragma unroll
    for (int i = 0; i < 4; i++)
#pragma unroll
        for (int j = 0; j < JF; j++)
            acc[i][j] = (floatx4){0.f, 0.f, 0.f, 0.f};

    // ---- precompute staging sources (kt added at issue) + LDS offsets ----
    const u16* sbase[NCH];
    int doff[NCH];
#pragma unroll
    for (int it = 0; it < NCH; it++) {
        const int idx = tid + it * 256;
        const int slot = idx & 3;
        doff[it] = idx * 8;
        if (idx < 512) {                     // A chunks (wave-uniform branch)
            const int row = idx >> 2;
            const int ch  = (slot ^ ((row >> 1) & 3)) * 8;   // inverse swizzle
            const long grow = SMAJ
                ? ((long)(row >> 1) * 512 + (blockIdx.y << 1) + (row & 1))
                : ((long)blockIdx.y * 128 + row);
            sbase[it] = Az + grow * K + ch;
        } else {                             // B chunks
            const int row = (idx - 512) >> 2;
            const int ch  = (slot ^ ((row >> 1) & 3)) * 8;
            sbase[it] = Bz + (long)(n0 + row) * K + ch;
        }
    }

    // ---- precompute swizzled fragment read offsets ----
    int aoff[4], boff[JF];
#pragma unroll
    for (int i = 0; i < 4; i++) {
        const int r = wm + i * 16 + lrow;
        aoff[i] = r * 32 + ((quad ^ ((r >> 1) & 3)) * 8);
    }
#pragma unroll
    for (int j = 0; j < JF; j++) {
        const int r = wn + j * 16 + lrow;
        boff[j] = 4096 + r * 32 + ((quad ^ ((r >> 1) & 3)) * 8);
    }

    // ---- prologue: stage tiles 0 and 1 ----
#pragma unroll
    for (int it = 0; it < NCH; it++)
        gload16(sbase[it], &lds[doff[it]]);
    if (K > 32) {
#pragma unroll
        for (int it = 0; it < NCH; it++)
            gload16(sbase[it] + 32, &lds[TILE + doff[it]]);
    }
    __builtin_amdgcn_sched_barrier(0);

    // ---- main loop: one barrier + one counted wait per K-step ----
    int bufc = 0;                            // buffer holding tile t
    for (int kt = 0; kt < K; kt += 32) {
        if (kt + 32 >= K) wait_vm<0>();      // last tile: drain
        else              wait_vm<NCH>();    // tile t done, t+1 in flight
        __builtin_amdgcn_s_barrier();
        __builtin_amdgcn_sched_barrier(0);

        if (kt + 64 < K) {                   // stage tile t+2
            int nb = bufc + 2; if (nb >= 3) nb -= 3;
            const int nbo = nb * TILE;
#pragma unroll
            for (int it = 0; it < NCH; it++)
                gload16(sbase[it] + kt + 64, &lds[nbo + doff[it]]);
        }
        __builtin_amdgcn_sched_barrier(0);   // stage issues before ds_reads

        const int b0 = bufc * TILE;
        short8 af[4], bfr[JF];
#pragma unroll
        for (int i = 0; i < 4; i++)
            af[i] = *(const short8*)&lds[b0 + aoff[i]];
#pragma unroll
        for (int j = 0; j < JF; j++)
            bfr[j] = *(const short8*)&lds[b0 + boff[j]];
#pragma unroll
        for (int i = 0; i < 4; i++)
#pragma unroll
            for (int j = 0; j < JF; j++)
                acc[i][j] = __builtin_amdgcn_mfma_f32_16x16x32_bf16(
                    af[i], bfr[j], acc[i][j], 0, 0, 0);

        __builtin_amdgcn_sched_barrier(0);   // keep compute inside the phase
        if (++bufc == 3) bufc = 0;
    }

    // D element: row = quad*4+r, col = lane&15 (verified m89/m91)
    const int z = blockIdx.z;
#pragma unroll
    for (int j = 0; j < JF; j++) {
        const int n = n0 + wn + j * 16 + lrow;
        int t = 0, jj = n, hG = 0;
        if (EPI == 8) { hG = n / 384; int rem = n - hG * 384; t = rem / 192; jj = rem - t * 192; }
        if (EPI == 9) { hG = n / 576; int rem = n - hG * 576; t = rem / 192; jj = rem - t * 192; }
        const int hl = jj / 12;
        const int cc = jj - hl * 12;
        float bv = 0.f;
        if (HASBIAS)
            bv = (EPI == 8 || EPI == 9) ? bias[t * 768 + colbase + hG * 192 + jj]
                                        : bias[colbase + n];
#pragma unroll
        for (int i = 0; i < 4; i++) {
            const int mb = wm + i * 16 + quad * 4;
#pragma unroll
            for (int r = 0; r < 4; r++) {
                const int ml = mb + r;
                float v = acc[i][j][r] + bv;
                if (RELU) v = fmaxf(v, 0.f);
                if (EPI == 0) {
                    const long m = (long)blockIdx.y * 128 + ml;
                    ((u16*)C)[m * Nb + n] = f2b(v);
                } else if (EPI == 1) {
                    const long m = (long)blockIdx.y * 128 + ml;
                    ((float*)C)[(long)z * sC + m * Nb + n] = v;
                } else if (EPI == 3) {
                    const int gm = blockIdx.y * 128 + ml;
                    const int s = gm >> 9, iL = gm & 511;
                    ((u16*)C)[(long)hl * 393216 + (long)(s * 12 + cc) * 512 + iL] = f2b(v);
                } else if (EPI == 4) {
                    const int m = blockIdx.y * 128 + ml;    // hl here = s-value
                    ((u16*)C)[((long)hl * 512 + m) * 768 + colbase + z * 12 + cc] = f2b(v);
                } else if (EPI == 8) {
                    const int s = ml >> 1, iL = (blockIdx.y << 1) + (ml & 1);
                    ((u16*)C)[(long)t * sC + ((long)(hG * 16 + hl) * 512 + iL) * 768 + s * 12 + cc] = f2b(v);
                } else if (EPI == 9) {
                    const int s = ml >> 1, l = (blockIdx.y << 1) + (ml & 1);
                    ((u16*)C)[(long)t * sC + (long)(hG * 16 + hl) * 393216 + (long)l * 768 + s * 12 + cc] = f2b(v);
                }
            }
        }
    }
}

// ---------------------------------------------------------------------------
// x (f32) -> xb (bf16), 8 elems/thread
// ---------------------------------------------------------------------------
__global__ __launch_bounds__(256) void cast_kernel(
    const float* __restrict__ X, u16* __restrict__ Xb)
{
    const long i = ((long)blockIdx.x * 256 + threadIdx.x) * 8;
    float4 a = *(const float4*)(X + i);
    float4 b = *(const float4*)(X + i + 4);
    u16 t8[8] = { f2b(a.x), f2b(a.y), f2b(a.z), f2b(a.w),
                  f2b(b.x), f2b(b.y), f2b(b.z), f2b(b.w) };
    *(uint4*)(Xb + i) = *(const uint4*)t8;
}

// ---------------------------------------------------------------------------
// 32x32 tiled transpose + cast: Out[c][r] = bf16(In[r][c]); Out ld = R
// ---------------------------------------------------------------------------
__global__ __launch_bounds__(256) void transpose_kernel(
    const float* __restrict__ In, u16* __restrict__ Out, int R, int Ccols)
{
    __shared__ u16 tile[32][33];
    int tx = threadIdx.x & 31;
    int ty = threadIdx.x >> 5;
    int c0 = blockIdx.x * 32;
    int r0 = blockIdx.y * 32;
#pragma unroll
    for (int rr = 0; rr < 32; rr += 8)
        tile[ty + rr][tx] = f2b(In[(long)(r0 + ty + rr) * Ccols + c0 + tx]);
    __syncthreads();
#pragma unroll
    for (int rr = 0; rr < 32; rr += 8)
        Out[(long)(c0 + ty + rr) * R + r0 + tx] = tile[tx][ty + rr];
}

// W[768][2304] -> wPqk[1536][768]: row p: hg=p/384, t=(p%384)/192, j=p%192
__global__ __launch_bounds__(256) void pack_qk_kernel(
    const float* __restrict__ In, u16* __restrict__ Out)
{
    __shared__ u16 tile[32][33];
    int tx = threadIdx.x & 31;
    int ty = threadIdx.x >> 5;
    int p0 = blockIdx.x * 32;
    int k0 = blockIdx.y * 32;
    int hg = p0 / 384, rem = p0 % 384;
    int t = rem / 192, j0 = rem % 192;
    int c0 = t * 768 + hg * 192 + j0;
#pragma unroll
    for (int rr = 0; rr < 32; rr += 8)
        tile[ty + rr][tx] = f2b(In[(long)(k0 + ty + rr) * 2304 + c0 + tx]);
    __syncthreads();
#pragma unroll
    for (int rr = 0; rr < 32; rr += 8)
        Out[(long)(p0 + ty + rr) * 768 + k0 + tx] = tile[tx][ty + rr];
}

// W[768][2304] -> wPv[768][768]: row p: hg=p/192, j=p%192 -> col 1536+hg*192+j
__global__ __launch_bounds__(256) void pack_v_kernel(
    const float* __restrict__ In, u16* __restrict__ Out)
{
    __shared__ u16 tile[32][33];
    int tx = threadIdx.x & 31;
    int ty = threadIdx.x >> 5;
    int p0 = blockIdx.x * 32;
    int k0 = blockIdx.y * 32;
    int hg = p0 / 192, j0 = p0 % 192;
    int c0 = 1536 + hg * 192 + j0;
#pragma unroll
    for (int rr = 0; rr < 32; rr += 8)
        tile[ty + rr][tx] = f2b(In[(long)(k0 + ty + rr) * 2304 + c0 + tx]);
    __syncthreads();
#pragma unroll
    for (int rr = 0; rr < 32; rr += 8)
        Out[(long)(p0 + ty + rr) * 768 + k0 + tx] = tile[tx][ty + rr];
}

// W[768][2304] -> wPcol[2304][768]: row p: hg=p/576, t=(p%576)/192, j=p%192
__global__ __launch_bounds__(256) void qkv_pack_kernel(
    const float* __restrict__ In, u16* __restrict__ Out)
{
    __shared__ u16 tile[32][33];
    int tx = threadIdx.x & 31;
    int ty = threadIdx.x >> 5;
    int p0 = blockIdx.x * 32;
    int k0 = blockIdx.y * 32;
    int hg = p0 / 576, r0 = p0 % 576;
    int t = r0 / 192, j0 = r0 % 192;
    int c0 = t * 768 + hg * 192 + j0;
#pragma unroll
    for (int rr = 0; rr < 32; rr += 8)
        tile[ty + rr][tx] = f2b(In[(long)(k0 + ty + rr) * 2304 + c0 + tx]);
    __syncthreads();
#pragma unroll
    for (int rr = 0; rr < 32; rr += 8)
        Out[(long)(p0 + ty + rr) * 768 + k0 + tx] = tile[tx][ty + rr];
}

// ---------------------------------------------------------------------------
// Row softmax over 512 (f32 scores -> bf16 probs); wave-per-row, 4 rows/block
// ---------------------------------------------------------------------------
__global__ __launch_bounds__(256) void softmax_kernel(
    const float* __restrict__ S, u16* __restrict__ P)
{
    const long r = (long)blockIdx.x * 4 + (threadIdx.x >> 6);
    const int lane = threadIdx.x & 63;
    const float* sp = S + r * 512 + lane * 8;
    float4 a = ((const float4*)sp)[0];
    float4 b = ((const float4*)sp)[1];
    float v[8] = {a.x, a.y, a.z, a.w, b.x, b.y, b.z, b.w};
    float mx = v[0];
#pragma unroll
    for (int e = 1; e < 8; e++) mx = fmaxf(mx, v[e]);
#pragma unroll
    for (int o = 32; o > 0; o >>= 1) mx = fmaxf(mx, __shfl_xor(mx, o, 64));
    float sum = 0.f;
#pragma unroll
    for (int e = 0; e < 8; e++) { v[e] = __expf(v[e] - mx); sum += v[e]; }
#pragma unroll
    for (int o = 32; o > 0; o >>= 1) sum += __shfl_xor(sum, o, 64);
    float inv = 1.0f / sum;
    uint4 o4;
    o4.x = (u32)f2b(v[0] * inv) | ((u32)f2b(v[1] * inv) << 16);
    o4.y = (u32)f2b(v[2] * inv) | ((u32)f2b(v[3] * inv) << 16);
    o4.z = (u32)f2b(v[4] * inv) | ((u32)f2b(v[5] * inv) << 16);
    o4.w = (u32)f2b(v[6] * inv) | ((u32)f2b(v[7] * inv) << 16);
    *(uint4*)(P + r * 512 + lane * 8) = o4;
}

// ---------------------------------------------------------------------------
// out = LN(Xa + Xb) * g + be ; wave-per-row (lane owns 12 elems), 4 rows/block
// ---------------------------------------------------------------------------
template<int AF, int BF, int OF>
__global__ __launch_bounds__(256) void ln_add_kernel(
    const void* __restrict__ Xa, const void* __restrict__ Xb,
    const float* __restrict__ g, const float* __restrict__ be,
    void* __restrict__ Out)
{
    const long r = (long)blockIdx.x * 4 + (threadIdx.x >> 6);
    const int lane = threadIdx.x & 63;
    const long c0 = r * 768 + lane * 12;
    float va[12], vb[12], v[12];
    if (AF) ld12f((const float*)Xa + c0, va);
    else    ld12b((const u16*)Xa + c0, va);
    if (BF) ld12f((const float*)Xb + c0, vb);
    else    ld12b((const u16*)Xb + c0, vb);
    float sm = 0.f, s2 = 0.f;
#pragma unroll
    for (int e = 0; e < 12; e++) {
        v[e] = va[e] + vb[e];
        sm += v[e]; s2 += v[e] * v[e];
    }
    wred2(sm, s2);
    float mean = sm * (1.0f / 768.0f);
    float var  = s2 * (1.0f / 768.0f) - mean * mean;
    float rstd = rsqrtf(var + LN_EPS);
    float gv[12], bv[12], o[12];
    ld12f(g + lane * 12, gv);
    ld12f(be + lane * 12, bv);
#pragma unroll
    for (int e = 0; e < 12; e++)
        o[e] = (v[e] - mean) * rstd * gv[e] + bv[e];
    if (OF) st12f((float*)Out + c0, o);
    else    st12b((u16*)Out + c0, o);
}

// ---------------------------------------------------------------------------
// Fused double-LN: y(f32) = LN2( X + LN1(A + B) ); also writes ybf (bf16).
// ---------------------------------------------------------------------------
__global__ __launch_bounds__(256) void ln_ln_kernel(
    const u16* __restrict__ A, const u16* __restrict__ B,
    const float* __restrict__ X,
    const float* __restrict__ g1, const float* __restrict__ be1,
    const float* __restrict__ g2, const float* __restrict__ be2,
    float* __restrict__ Out, u16* __restrict__ Outb)
{
    const long r = (long)blockIdx.x * 4 + (threadIdx.x >> 6);
    const int lane = threadIdx.x & 63;
    const long c0 = r * 768 + lane * 12;
    float ua[12], ub[12], u[12];
    ld12b(A + c0, ua);
    ld12b(B + c0, ub);
    float sm = 0.f, s2 = 0.f;
#pragma unroll
    for (int e = 0; e < 12; e++) {
        u[e] = ua[e] + ub[e];
        sm += u[e]; s2 += u[e] * u[e];
    }
    wred2(sm, s2);
    float mean1 = sm * (1.0f / 768.0f);
    float var1  = s2 * (1.0f / 768.0f) - mean1 * mean1;
    float rstd1 = rsqrtf(var1 + LN_EPS);

    float xx[12], g1v[12], b1v[12], w[12];
    ld12f(X + c0, xx);
    ld12f(g1 + lane * 12, g1v);
    ld12f(be1 + lane * 12, b1v);
    sm = 0.f; s2 = 0.f;
#pragma unroll
    for (int e = 0; e < 12; e++) {
        float tv = (u[e] - mean1) * rstd1 * g1v[e] + b1v[e];
        w[e] = xx[e] + tv;
        sm += w[e]; s2 += w[e] * w[e];
    }
    wred2(sm, s2);
    float mean2 = sm * (1.0f / 768.0f);
    float var2  = s2 * (1.0f / 768.0f) - mean2 * mean2;
    float rstd2 = rsqrtf(var2 + LN_EPS);

    float g2v[12], b2v[12], o[12];
    ld12f(g2 + lane * 12, g2v);
    ld12f(be2 + lane * 12, b2v);
#pragma unroll
    for (int e = 0; e < 12; e++)
        o[e] = (w[e] - mean2) * rstd2 * g2v[e] + b2v[e];
    st12f(Out + c0, o);
    st12b(Outb + c0, o);
}

// ---------------------------------------------------------------------------
// Col attention. Slices: [h'][l][s*12+c], h' = blockIdx.x>>9 (any head count).
// Block = (h', l), 64 threads; thread i = query S-row. Out col = hbase+h'*12.
// ---------------------------------------------------------------------------
__global__ __launch_bounds__(64) void col_attn_kernel(
    const u16* __restrict__ qc, const u16* __restrict__ kc,
    const u16* __restrict__ vc, u16* __restrict__ Out, int hbase)
{
    const int hh = blockIdx.x >> 9;
    const int l  = blockIdx.x & 511;
    const int i  = threadIdx.x;
    const long base = ((long)hh * 512 + l) * 768 + (long)i * 12;
    __shared__ float Ks[64][12];
    __shared__ float Vs[64][12];
    float q[12], kk[12], vv[12];
    ld12b(qc + base, q);
    ld12b(kc + base, kk);
    ld12b(vc + base, vv);
#pragma unroll
    for (int c = 0; c < 12; c++) { Ks[i][c] = kk[c]; Vs[i][c] = vv[c]; }
    __syncthreads();
    float sc[64];
#pragma unroll
    for (int j = 0; j < 64; j++) {
        float a = 0.f;
#pragma unroll
        for (int c = 0; c < 12; c++) a += q[c] * Ks[j][c];
        sc[j] = a;
    }
    float m = sc[0];
#pragma unroll
    for (int j = 1; j < 64; j++) m = fmaxf(m, sc[j]);
    float sum = 0.f;
#pragma unroll
    for (int j = 0; j < 64; j++) { sc[j] = __expf(sc[j] - m); sum += sc[j]; }
    float inv = 1.0f / sum;
    float o[12];
#pragma unroll
    for (int c = 0; c < 12; c++) o[c] = 0.f;
#pragma unroll
    for (int j = 0; j < 64; j++) {
        float p = sc[j] * inv;
#pragma unroll
        for (int c = 0; c < 12; c++) o[c] += p * Vs[j][c];
    }
    u16* op = Out + ((long)i * 512 + l) * 768 + hbase + hh * 12;
    st12b(op, o);
}

// ---------------------------------------------------------------------------
extern "C" void kernel_launch(void* const* d_in, const int* in_sizes, int n_in,
                              void* d_out, int out_size, void* d_ws, size_t ws_size,
                              hipStream_t stream)
{
    (void)in_sizes; (void)n_in; (void)out_size;

    const float* x     = (const float*)d_in[0];
    const float* w_row = (const float*)d_in[1];
    const float* b_row = (const float*)d_in[2];
    const float* w_col = (const float*)d_in[3];
    const float* b_col = (const float*)d_in[4];
    const float* g_a1  = (const float*)d_in[5];
    const float* be_a1 = (const float*)d_in[6];
    const float* g_a2  = (const float*)d_in[7];
    const float* be_a2 = (const float*)d_in[8];
    const float* w1    = (const float*)d_in[9];
    const float* b1f   = (const float*)d_in[10];
    const float* w2    = (const float*)d_in[11];
    const float* b2f_  = (const float*)d_in[12];
    const float* g_n1  = (const float*)d_in[13];
    const float* be_n1 = (const float*)d_in[14];
    const float* g_n2  = (const float*)d_in[15];
    const float* be_n2 = (const float*)d_in[16];
    float* outp = (float*)d_out;

    // ---- workspace layout: merged (all 64 heads, ~336 MB) if ws_size
    //      allows, else the proven per-16-head fallback (~180 MB) ----
    char* wp = (char*)d_ws;
    auto alloc = [&](size_t bytes) -> void* {
        void* p = (void*)wp;
        wp += (bytes + 255) & ~(size_t)255;
        return p;
    };
    u16*   wPqk   = (u16*)alloc((size_t)1536 * 768 * 2);
    u16*   wPv    = (u16*)alloc((size_t)768 * 768 * 2);
    u16*   wPcol  = (u16*)alloc((size_t)2304 * 768 * 2);
    u16*   w1T    = (u16*)alloc((size_t)3072 * 768 * 2);
    u16*   w2T    = (u16*)alloc((size_t)768 * 3072 * 2);
    u16*   bufA   = (u16*)alloc((size_t)32768 * 768 * 2);       // rowout/colout/ffb
    u16*   bufB   = (u16*)alloc((size_t)32768 * 768 * 2);       // xb -> out1 -> ybf

    const size_t base_used   = (size_t)(wp - (char*)d_ws);
    const size_t need_merged = base_used
        + (size_t)3 * 64 * 393216 * 2      // qkvg (64 heads)
        + (size_t)64 * 512 * 512 * 4 + 512;// scores + align slack
    const bool merged = (ws_size >= need_merged);
    const int  NH = merged ? 64 : 16;      // heads per launch scope
    const int  NG = merged ? 1 : 4;        // head-group iterations
    const long QS = (long)NH * 393216;     // Q|K|V region stride (elems)

    u16*   qkvg   = (u16*)alloc((size_t)3 * NH * 393216 * 2);
    float* scores = (float*)alloc((size_t)NH * 512 * 512 * 4);
    u16*   probs  = merged ? bufB          // merged: xb dead before softmax
                           : (u16*)alloc((size_t)16 * 512 * 512 * 2);
    u16*   hidden = qkvg;    // alias: FFN after attention; fallback spans scores
    u16*   xb     = bufB;
    u16*   ybf    = bufB;
    float* y      = outp;

    // ---- weight packing (f32 -> bf16) ----
    pack_qk_kernel<<<dim3(48, 24), 256, 0, stream>>>(w_row, wPqk);
    pack_v_kernel<<<dim3(24, 24), 256, 0, stream>>>(w_row, wPv);
    qkv_pack_kernel<<<dim3(72, 24), 256, 0, stream>>>(w_col, wPcol);
    transpose_kernel<<<dim3(96, 24), 256, 0, stream>>>(w1, w1T, 768, 3072);
    transpose_kernel<<<dim3(24, 96), 256, 0, stream>>>(w2, w2T, 3072, 768);
    cast_kernel<<<12288, 256, 0, stream>>>(x, xb);

    // ---- row (tied) attention ----
    for (int g = 0; g < NG; g++) {
        // Q,K (Nb=24*NH, s-major, head-major writes at region stride QS)
        gemm_dma<192, 8, 0, 1, 1><<<dim3(NH / 8, 256), 256, 0, stream>>>(
            xb, wPqk + (long)g * 384 * 768, b_row, qkvg,
            24 * NH, 768, 0, 0, QS, g * 192);
        // V (Nb=12*NH, s-blocked, dense V^T writes)
        gemm_dma<192, 3, 0, 1, 0><<<dim3(NH / 16, 256), 256, 0, stream>>>(
            xb, wPv + (long)g * 192 * 768, b_row, qkvg + 2 * QS,
            12 * NH, 768, 0, 0, 0, 1536 + g * 192);
        // scores = Q @ K^T (batched over NH heads)
        gemm_dma<128, 1, 0, 0, 0><<<dim3(4, 4, NH), 256, 0, stream>>>(
            qkvg, qkvg + QS, nullptr, scores,
            512, 768, (long)512 * 768, (long)512 * 768, (long)512 * 512, 0);
        softmax_kernel<<<NH * 128, 256, 0, stream>>>(scores, probs);
        // rowout = P @ V^T^T (batched over NH heads)
        gemm_dma<128, 4, 0, 0, 0><<<dim3(6, 4, NH), 256, 0, stream>>>(
            probs, qkvg + 2 * QS, nullptr, bufA,
            768, 512, (long)512 * 512, (long)768 * 512, 0, g * 192);
    }
    // out1 = LN(x + rowout)   (xb dead; bufB becomes out1)
    ln_add_kernel<1, 0, 0><<<8192, 256, 0, stream>>>(x, bufA, g_a1, be_a1, bufB);

    // ---- col attention ----
    for (int g = 0; g < NG; g++) {
        gemm_dma<192, 9, 0, 1, 1><<<dim3(3 * NH / 16, 256), 256, 0, stream>>>(
            bufB, wPcol + (long)g * 576 * 768, b_col, qkvg,
            36 * NH, 768, 0, 0, QS, g * 192);
        col_attn_kernel<<<NH * 512, 64, 0, stream>>>(
            qkvg, qkvg + QS, qkvg + 2 * QS, bufA, g * 192);
    }
    // y = LN(x + LN(out1 + colout)) -> d_out (f32) + ybf (bf16 alias)
    ln_ln_kernel<<<8192, 256, 0, stream>>>(
        bufB, bufA, x, g_a2, be_a2, g_n1, be_n1, y, ybf);

    // ---- FFN: merged -> 2 chunks of 16384 rows; fallback -> 4 x 8192 ----
    const int nchunk = merged ? 2 : 4;
    const int crows  = 32768 / nchunk;
    for (int mc = 0; mc < nchunk; mc++) {
        const long off = (long)mc * crows * 768;
        gemm_dma<192, 0, 1, 1, 0><<<dim3(16, crows / 128), 256, 0, stream>>>(
            ybf + off, w1T, b1f, hidden, 3072, 768, 0, 0, 0, 0);
        gemm_dma<192, 0, 0, 1, 0><<<dim3(4, crows / 128), 256, 0, stream>>>(
            hidden, w2T, b2f_, bufA + off, 768, 3072, 0, 0, 0, 0);
    }
    // final: out = LN(y + ffb), in-place over d_out (per-row, block-local)
    ln_add_kernel<1, 0, 1><<<8192, 256, 0, stream>>>(y, bufA, g_n2, be_n2, outp);
}